// Round 3
// baseline (79.643 us; speedup 1.0000x reference)
//
#include <hip/hip_runtime.h>
#include <hip/hip_bf16.h>

// out[b,c] = sum_k w[b,k] * BivariateNormalPDF(X[b,c]; params[b,k])
// B=512, K=64, C=2048.
//
// Two-kernel plan:
//  1) prep_kernel: per (b,k), compute packed-pair coefficients into d_ws:
//     [is1,is1, is2,is2, -mm1,-mm1, -mm2,-mm2, 2r,2r, wn,wn, pad4]  (64 B)
//  2) mixture_kernel: k-loop reads coefficients via wave-uniform loads
//     (-> s_load, scalar pipe; no LDS, no per-lane VMEM in the loop).
//     Inner eval: e = 2r*dx*dy - (dx^2+dy^2); acc += wn * exp2(e),
//     all in packed fp32 (v_pk_fma_f32 / v_pk_mul_f32).

typedef float v2f __attribute__((ext_vector_type(2)));

constexpr int B = 512;
constexpr int K = 64;
constexpr int C = 2048;
constexpr int BLOCK = 256;
constexpr int HALVES = 2;        // each batch's C range split across 2 blocks
constexpr int CH = C / HALVES;   // 1024 points per block -> 4 per thread

__global__ __launch_bounds__(256) void prep_kernel(
    const float* __restrict__ mo,   // (B, K, 6)
    float* __restrict__ P)          // (B*K, 16)
{
    const int i = blockIdx.x * 256 + threadIdx.x;   // 0 .. B*K-1
    const float* p = mo + (size_t)i * 6;
    const float w  = p[0];
    const float m1 = p[1];
    const float m2 = p[2];
    const float s1 = p[3];
    const float s2 = p[4];
    const float r  = p[5];

    const float omr2 = fmaf(-r, r, 1.0f);
    const float inv  = 1.0f / omr2;
    const float a2   = 0.7213475204444817f * inv;   // 0.5*log2(e)/omr2
    const float sc   = sqrtf(a2);
    const float is1  = sc / s1;
    const float is2  = sc / s2;
    const float nm1  = -(m1 * is1);
    const float nm2  = -(m2 * is2);
    const float r2   = 2.0f * r;
    const float wn   = w * 0.15915494309189535f / (s1 * s2 * sqrtf(omr2));

    float4* q = (float4*)(P + (size_t)i * 16);
    q[0] = make_float4(is1, is1, is2, is2);
    q[1] = make_float4(nm1, nm1, nm2, nm2);
    q[2] = make_float4(r2, r2, wn, wn);
    // q[3] unused (padding for 64 B records)
}

__global__ __launch_bounds__(BLOCK) void mixture_kernel(
    const float* __restrict__ X,    // (B, C, 2)
    const float* __restrict__ P,    // (B*K, 16) packed-pair coefficients
    float* __restrict__ out)        // (B, C)
{
    const int bid = blockIdx.x;
    const int b   = bid >> 1;
    const int h   = bid & 1;
    const int t   = threadIdx.x;

    // 4 points per thread: 2 coalesced float4 loads, repacked (x,x)/(y,y).
    const float4* Xb = (const float4*)(X + (size_t)b * C * 2 + (size_t)h * CH * 2);
    const float4 xv0 = Xb[t];
    const float4 xv1 = Xb[t + BLOCK];

    const v2f xs0 = { xv0.x, xv0.z };
    const v2f ys0 = { xv0.y, xv0.w };
    const v2f xs1 = { xv1.x, xv1.z };
    const v2f ys1 = { xv1.y, xv1.w };
    v2f acc0 = { 0.0f, 0.0f };
    v2f acc1 = { 0.0f, 0.0f };

    // Wave-uniform coefficient base for this batch.
    const v2f* __restrict__ Pb = (const v2f*)(P + (size_t)b * K * 16);

#pragma unroll 4
    for (int k = 0; k < K; ++k) {
        const v2f IS1 = Pb[k * 8 + 0];
        const v2f IS2 = Pb[k * 8 + 1];
        const v2f NM1 = Pb[k * 8 + 2];
        const v2f NM2 = Pb[k * 8 + 3];
        const v2f R2  = Pb[k * 8 + 4];
        const v2f WN  = Pb[k * 8 + 5];

        {
            const v2f dx = __builtin_elementwise_fma(xs0, IS1, NM1);
            const v2f dy = __builtin_elementwise_fma(ys0, IS2, NM2);
            const v2f pq = dx * dy;
            v2f u        = dx * dx;
            u            = __builtin_elementwise_fma(dy, dy, u);
            const v2f e  = __builtin_elementwise_fma(R2, pq, -u);
            v2f ex;
            ex.x = __builtin_amdgcn_exp2f(e.x);
            ex.y = __builtin_amdgcn_exp2f(e.y);
            acc0 = __builtin_elementwise_fma(WN, ex, acc0);
        }
        {
            const v2f dx = __builtin_elementwise_fma(xs1, IS1, NM1);
            const v2f dy = __builtin_elementwise_fma(ys1, IS2, NM2);
            const v2f pq = dx * dy;
            v2f u        = dx * dx;
            u            = __builtin_elementwise_fma(dy, dy, u);
            const v2f e  = __builtin_elementwise_fma(R2, pq, -u);
            v2f ex;
            ex.x = __builtin_amdgcn_exp2f(e.x);
            ex.y = __builtin_amdgcn_exp2f(e.y);
            acc1 = __builtin_elementwise_fma(WN, ex, acc1);
        }
    }

    float2* ob = (float2*)(out + (size_t)b * C + (size_t)h * CH);
    ob[t]         = make_float2(acc0.x, acc0.y);
    ob[t + BLOCK] = make_float2(acc1.x, acc1.y);
}

extern "C" void kernel_launch(void* const* d_in, const int* in_sizes, int n_in,
                              void* d_out, int out_size, void* d_ws, size_t ws_size,
                              hipStream_t stream) {
    const float* mo = (const float*)d_in[0];   // (B,K,6)
    const float* X  = (const float*)d_in[1];   // (B,C,2)
    float* out      = (float*)d_out;           // (B,C)
    float* P        = (float*)d_ws;            // (B*K,16) = 2 MB scratch

    prep_kernel<<<dim3(B * K / 256), dim3(256), 0, stream>>>(mo, P);
    mixture_kernel<<<dim3(B * HALVES), dim3(BLOCK), 0, stream>>>(X, P, out);
}

// Round 4
// 74.542 us; speedup vs baseline: 1.0684x; 1.0684x over previous
//
#include <hip/hip_runtime.h>
#include <hip/hip_bf16.h>

// out[b,c] = sum_k w[b,k] * BivariateNormalPDF(X[b,c]; params[b,k])
// B=512, K=64, C=2048.
//
// Structure (round 4): one block per batch b, 256 threads, 8 points/thread.
// Threads 0..63 precompute per-k coefficients into LDS (2 KB):
//   [is1, is2, -m1*is1, -m2*is2], [2r, wn, -, -]
// with is = sqrt(0.5*log2e/(1-r^2))/s, wn = w/(2*pi*s1*s2*sqrt(1-r^2)).
// k-loop: software-pipelined LDS coefficient reads (prefetch k+1 while
// computing k), packed fp32 math (v_pk_fma_f32/v_pk_mul_f32), native exp2:
//   e = 2r*dx*dy - (dx*dx + dy*dy);  acc += wn * exp2(e).
// Per k-iter per wave: 2 ds_read_b128 + 28 pk + 8 exp — LDS pipe and VALU
// balanced at ~5 us each across the chip.

typedef float v2f __attribute__((ext_vector_type(2)));

constexpr int B = 512;
constexpr int K = 64;
constexpr int C = 2048;
constexpr int BLOCK = 256;
constexpr int PTS = 8;                 // points per thread
constexpr int NG = PTS / 2;            // packed pairs per thread

__global__ __launch_bounds__(BLOCK) void mixture_kernel(
    const float* __restrict__ mo,   // (B, K, 6)
    const float* __restrict__ X,    // (B, C, 2)
    float* __restrict__ out)        // (B, C)
{
    __shared__ float4 P[K][2];

    const int b = blockIdx.x;
    const int t = threadIdx.x;

    if (t < K) {
        const float* p = mo + ((size_t)(b * K + t)) * 6;
        const float w  = p[0];
        const float m1 = p[1];
        const float m2 = p[2];
        const float s1 = p[3];
        const float s2 = p[4];
        const float r  = p[5];

        const float omr2 = fmaf(-r, r, 1.0f);
        const float inv  = 1.0f / omr2;
        const float a2   = 0.7213475204444817f * inv;   // 0.5*log2(e)/omr2
        const float sc   = sqrtf(a2);
        const float is1  = sc / s1;
        const float is2  = sc / s2;
        const float wn   = w * 0.15915494309189535f / (s1 * s2 * sqrtf(omr2));

        P[t][0] = make_float4(is1, is2, -(m1 * is1), -(m2 * is2));
        P[t][1] = make_float4(2.0f * r, wn, 0.0f, 0.0f);
    }
    __syncthreads();

    // 8 points/thread: 4 coalesced float4 loads (2 points each), repacked
    // into (x,x)/(y,y) packed pairs.
    const float4* Xb = (const float4*)(X + (size_t)b * C * 2);
    v2f xs[NG], ys[NG], acc[NG];
#pragma unroll
    for (int j = 0; j < NG; ++j) {
        const float4 xv = Xb[t + j * BLOCK];
        xs[j]  = (v2f){xv.x, xv.z};
        ys[j]  = (v2f){xv.y, xv.w};
        acc[j] = (v2f){0.0f, 0.0f};
    }

    // Software-pipelined k-loop: prefetch k+1's coefficients during k's math.
    float4 c0 = P[0][0];
    float4 c1 = P[0][1];
#pragma unroll 8
    for (int k = 0; k < K; ++k) {
        const int kn = (k + 1) & (K - 1);      // wraps to 0 on last iter (unused)
        const float4 n0 = P[kn][0];
        const float4 n1 = P[kn][1];

        const v2f IS1 = { c0.x, c0.x };
        const v2f IS2 = { c0.y, c0.y };
        const v2f NM1 = { c0.z, c0.z };
        const v2f NM2 = { c0.w, c0.w };
        const v2f R2  = { c1.x, c1.x };
        const v2f WN  = { c1.y, c1.y };

#pragma unroll
        for (int j = 0; j < NG; ++j) {
            const v2f dx = __builtin_elementwise_fma(xs[j], IS1, NM1);
            const v2f dy = __builtin_elementwise_fma(ys[j], IS2, NM2);
            const v2f pq = dx * dy;
            v2f u        = dx * dx;
            u            = __builtin_elementwise_fma(dy, dy, u);
            const v2f e  = __builtin_elementwise_fma(R2, pq, -u);
            v2f ex;
            ex.x = __builtin_amdgcn_exp2f(e.x);
            ex.y = __builtin_amdgcn_exp2f(e.y);
            acc[j] = __builtin_elementwise_fma(WN, ex, acc[j]);
        }

        c0 = n0;
        c1 = n1;
    }

    float2* ob = (float2*)(out + (size_t)b * C);
#pragma unroll
    for (int j = 0; j < NG; ++j)
        ob[t + j * BLOCK] = make_float2(acc[j].x, acc[j].y);
}

extern "C" void kernel_launch(void* const* d_in, const int* in_sizes, int n_in,
                              void* d_out, int out_size, void* d_ws, size_t ws_size,
                              hipStream_t stream) {
    const float* mo = (const float*)d_in[0];   // (B,K,6)
    const float* X  = (const float*)d_in[1];   // (B,C,2)
    float* out      = (float*)d_out;           // (B,C)

    mixture_kernel<<<dim3(B), dim3(BLOCK), 0, stream>>>(mo, X, out);
}